// Round 9
// baseline (184.159 us; speedup 1.0000x reference)
//
#include <hip/hip_runtime.h>
#include <hip/hip_bf16.h>

typedef float f32x4 __attribute__((ext_vector_type(4)));
typedef short bf16x8 __attribute__((ext_vector_type(8)));

#define B_DIM 4096
#define C_DIM 1000
#define CP 1024
#define K1 2048
#define EPS 1e-6f

__device__ __forceinline__ float wsum(float v) {
#pragma unroll
  for (int o = 32; o > 0; o >>= 1) v += __shfl_xor(v, o, 64);
  return v;
}
__device__ __forceinline__ float wmax(float v) {
#pragma unroll
  for (int o = 32; o > 0; o >>= 1) v = fmaxf(v, __shfl_xor(v, o, 64));
  return v;
}

__device__ __forceinline__ void load_lds16(const void* g, void* l) {
  __builtin_amdgcn_global_load_lds(
      (const __attribute__((address_space(1))) unsigned int*)g,
      (__attribute__((address_space(3))) unsigned int*)l, 16, 0, 0);
}

// ---- merged prep: 4 units/block (256 thr). units [0,CP)=class, [CP,CP+B)=b ----
__global__ void prep_all(const float* __restrict__ sig,
                         const float* __restrict__ lr,
                         const float* __restrict__ pe,
                         __hip_bfloat16* __restrict__ wsig,
                         float* __restrict__ expd,
                         __hip_bfloat16* __restrict__ elc,
                         __hip_bfloat16* __restrict__ pen,
                         float* __restrict__ ssb,
                         __hip_bfloat16* __restrict__ elb) {
  const int t = threadIdx.x & 63;
  const int unit = blockIdx.x * 4 + (threadIdx.x >> 6);
  if (unit < CP) {
    const int c = unit;
    if (c >= C_DIM) {  // zero padding rows so the GEMM reads clean zeros
      for (int i = t; i < K1; i += 64) wsig[(size_t)c * K1 + i] = __float2bfloat16(0.f);
      if (t < 32) expd[c * 32 + t] = 0.f;
      elc[(size_t)c * 128 + t] = __float2bfloat16(0.f);
      elc[(size_t)c * 128 + 64 + t] = __float2bfloat16(0.f);
      return;
    }
    float lv = (t < 32) ? lr[c * 32 + t] : -3.0e38f;
    float mx = wmax(lv);
    float ev = (t < 32) ? expf(lv - mx) : 0.f;
    float sden = wsum(ev);
    float res = ev / sden;
    if (t < 31) {
      float d = lr[c * 32 + t] - lr[c * 32 + t + 1];
      expd[c * 32 + t] = 1.f / (1.f + expf(-d));
    } else if (t == 31) {
      expd[c * 32 + 31] = 0.f;
    }
    float es = 0.f, ls = 0.f;
    for (int l = 0; l < 32; ++l) {
      float s = sig[((size_t)c * 32 + l) * 64 + t];
      float nrm = fmaxf(sqrtf(wsum(s * s)), 1e-12f);
      float resl = __shfl(res, l, 64);
      wsig[((size_t)c * 32 + l) * 64 + t] = __float2bfloat16(s / nrm * resl);
      if (l < 16) es += s; else ls += s;
    }
    es *= (1.f / 16.f); ls *= (1.f / 16.f);
    float en = fmaxf(sqrtf(wsum(es * es)), 1e-12f);
    float ln2 = fmaxf(sqrtf(wsum(ls * ls)), 1e-12f);
    elc[(size_t)c * 128 + t] = __float2bfloat16(es / en);
    elc[(size_t)c * 128 + 64 + t] = __float2bfloat16(ls / ln2);
  } else {
    const int b = unit - CP;
    float v[32];
#pragma unroll
    for (int l = 0; l < 32; ++l) v[l] = pe[((size_t)b * 32 + l) * 64 + t];
    float nrm[32];
#pragma unroll
    for (int l = 0; l < 32; ++l) nrm[l] = sqrtf(wsum(v[l] * v[l]));
#pragma unroll
    for (int l = 0; l < 32; ++l)
      pen[((size_t)b * 32 + l) * 64 + t] = __float2bfloat16(v[l] / fmaxf(nrm[l], 1e-12f));
#pragma unroll
    for (int l = 0; l < 31; ++l) {
      float dot = wsum(v[l] * v[l + 1]);
      float cosv = dot / (fmaxf(nrm[l], 1e-8f) * fmaxf(nrm[l + 1], 1e-8f));
      if (t == 0) ssb[(size_t)b * 32 + l] = (cosv + 1.0f) * 0.5f;
    }
    if (t == 0) ssb[(size_t)b * 32 + 31] = 0.0f;
    float es = 0.f, ls = 0.f;
#pragma unroll
    for (int l = 0; l < 16; ++l) es += v[l];
#pragma unroll
    for (int l = 16; l < 32; ++l) ls += v[l];
    es *= (1.f / 16.f); ls *= (1.f / 16.f);
    float en = fmaxf(sqrtf(wsum(es * es)), 1e-12f);
    float ln2 = fmaxf(sqrtf(wsum(ls * ls)), 1e-12f);
    elb[(size_t)b * 128 + t] = __float2bfloat16(es / en);
    elb[(size_t)b * 128 + 64 + t] = __float2bfloat16(ls / ln2);
  }
}

// ---- main fused: 64x64 tile, 4 waves (32x32 each), BK=64, 2-buf, 4 blk/CU ----
// R8 lesson: 2 big lockstep barrier groups/CU leave ~70% issue idle. Smaller
// blocks -> 4 independent groups/CU. Literal buffer indices -> all ds_read
// addrs fold to per-lane-const + offset-imm (max 32752 < 64KB), zero addr VALU.
// R6/R7 lesson: never constrain VGPR below need (spills -> 8x HBM traffic).
__global__ __launch_bounds__(256, 4)
void basin_main(const __hip_bfloat16* __restrict__ pen,
                const __hip_bfloat16* __restrict__ wsig,
                const __hip_bfloat16* __restrict__ elb,
                const __hip_bfloat16* __restrict__ elc,
                const float* __restrict__ ssb,
                const float* __restrict__ expd,
                const float* __restrict__ cm,
                const float* __restrict__ proto,
                float* __restrict__ out) {
  __shared__ __align__(16) char smem[32768];  // 2 x (A 8KB + B 8KB)
  const int t = threadIdx.x;
  const int lane = t & 63;
  const int w = t >> 6;                // 0..3
  const int wm = w >> 1, wn = w & 1;   // 2M x 2N waves, each 32x32
  const int brow = blockIdx.x * 64;
  const int bcol = blockIdx.y * 64;
  // staging: 8 threads per 128B row, 256 thr = 32 rows/inst; 2 insts per panel.
  const int srow = t >> 3;                          // 0..31
  const int selem = (((t & 7) ^ (srow & 7)) << 3);  // pre-swizzled source elem
  const int l15 = lane & 15;
  const int gq = lane >> 4;                         // quarter 0..3

  // per-lane ds_read byte offsets (loop-invariant; static-indexed)
  int offA[2][2], offB[2][2];
#pragma unroll
  for (int m = 0; m < 2; ++m)
#pragma unroll
    for (int kk = 0; kk < 2; ++kk) {
      int rowa = wm * 32 + m * 16 + l15;
      int rowb = wn * 32 + m * 16 + l15;
      int g = kk * 4 + gq;
      offA[m][kk] = rowa * 128 + ((g ^ (rowa & 7)) << 4);
      offB[m][kk] = rowb * 128 + ((g ^ (rowb & 7)) << 4);
    }

  f32x4 acc1[2][2] = {};
  f32x4 acc2[2][2] = {};

// buffer BI is a LITERAL. A at BI*16384, B at BI*16384+8192 (8KB each).
#define STAGE_T(kt, BI)                                                                   \
  do {                                                                                    \
    load_lds16(pen + (size_t)(brow + srow) * K1 + (kt) * 64 + selem,                      \
               smem + (BI) * 16384 + t * 16);                                             \
    load_lds16(pen + (size_t)(brow + 32 + srow) * K1 + (kt) * 64 + selem,                 \
               smem + (BI) * 16384 + 4096 + t * 16);                                      \
    load_lds16(wsig + (size_t)(bcol + srow) * K1 + (kt) * 64 + selem,                     \
               smem + (BI) * 16384 + 8192 + t * 16);                                      \
    load_lds16(wsig + (size_t)(bcol + 32 + srow) * K1 + (kt) * 64 + selem,                \
               smem + (BI) * 16384 + 12288 + t * 16);                                     \
  } while (0)

#define STAGE_H(kt, BI)                                                                   \
  do {                                                                                    \
    load_lds16(elb + (size_t)(brow + srow) * 128 + (kt) * 64 + selem,                     \
               smem + (BI) * 16384 + t * 16);                                             \
    load_lds16(elb + (size_t)(brow + 32 + srow) * 128 + (kt) * 64 + selem,                \
               smem + (BI) * 16384 + 4096 + t * 16);                                      \
    load_lds16(elc + (size_t)(bcol + srow) * 128 + (kt) * 64 + selem,                     \
               smem + (BI) * 16384 + 8192 + t * 16);                                      \
    load_lds16(elc + (size_t)(bcol + 32 + srow) * 128 + (kt) * 64 + selem,                \
               smem + (BI) * 16384 + 12288 + t * 16);                                     \
  } while (0)

#define COMPUTE(ACC, BI)                                                                  \
  do {                                                                                    \
    _Pragma("unroll") for (int kk = 0; kk < 2; ++kk) {                                    \
      bf16x8 af[2], bg[2];                                                                \
      af[0] = *(const bf16x8*)(smem + (BI) * 16384 + offA[0][kk]);                        \
      af[1] = *(const bf16x8*)(smem + (BI) * 16384 + offA[1][kk]);                        \
      bg[0] = *(const bf16x8*)(smem + (BI) * 16384 + 8192 + offB[0][kk]);                 \
      bg[1] = *(const bf16x8*)(smem + (BI) * 16384 + 8192 + offB[1][kk]);                 \
      _Pragma("unroll") for (int m = 0; m < 2; ++m)                                       \
        _Pragma("unroll") for (int n = 0; n < 2; ++n)                                     \
          ACC[m][n] = __builtin_amdgcn_mfma_f32_16x16x32_bf16(af[m], bg[n], ACC[m][n], 0, 0, 0); \
    }                                                                                     \
  } while (0)

#define KSTEP(kt, BI, OTHER)                                                              \
  do {                                                                                    \
    asm volatile("s_waitcnt vmcnt(0)" ::: "memory"); /* stage(kt) landed */               \
    __builtin_amdgcn_s_barrier();                    /* all waves: prev reads done */     \
    __builtin_amdgcn_sched_barrier(0);                                                    \
    if ((kt) + 1 < 32) STAGE_T((kt) + 1, OTHER);     /* issue next before compute */      \
    COMPUTE(acc1, BI);                                                                    \
  } while (0)

  // ---- triadic GEMM: K=2048, 32 steps of BK=64, dbuf, unroll x2 ----
  STAGE_T(0, 0);
  for (int kt = 0; kt < 32; kt += 2) {
    KSTEP(kt, 0, 1);
    KSTEP(kt + 1, 1, 0);
  }
  __syncthreads();  // everyone done with triadic reads

  // ---- hier GEMM: K=128 = 2 steps ----
  STAGE_H(0, 0);
  STAGE_H(1, 1);
  asm volatile("s_waitcnt vmcnt(4)" ::: "memory");  // stage_h(0) landed
  __builtin_amdgcn_s_barrier();
  __builtin_amdgcn_sched_barrier(0);
  COMPUTE(acc2, 0);
  asm volatile("s_waitcnt vmcnt(0)" ::: "memory");
  __builtin_amdgcn_s_barrier();
  __builtin_amdgcn_sched_barrier(0);
  COMPUTE(acc2, 1);
  __syncthreads();  // done reading before epilogue overwrites smem

  // ---- epilogue: stage ss/exp rows + cantor scalars in LDS ----
  float* ss_l = (float*)smem;            // [64][36] padded stride (9216B)
  float* ex_l = (float*)(smem + 9216);   // [64][36]
  float* cm_l = (float*)(smem + 18432);  // [64]
  float* pr_l = (float*)(smem + 18688);  // [64]
  for (int i = t; i < 2048; i += 256) {
    int r = i >> 5, l = i & 31;
    ss_l[r * 36 + l] = ssb[(size_t)(brow + r) * 32 + l];
    ex_l[r * 36 + l] = expd[(size_t)(bcol + r) * 32 + l];
  }
  if (t < 64) cm_l[t] = cm[brow + t];
  else if (t < 128) pr_l[t - 64] = (bcol + t - 64 < C_DIM) ? proto[bcol + t - 64] : 0.f;
  __syncthreads();

  const int col0 = wn * 32 + l15;
  const int row0 = wm * 32 + (gq << 2);
#pragma unroll
  for (int m = 0; m < 2; ++m) {
    float ssum[4][2];
#pragma unroll
    for (int j = 0; j < 4; ++j)
#pragma unroll
      for (int n = 0; n < 2; ++n) ssum[j][n] = 0.f;
#pragma unroll
    for (int l4 = 0; l4 < 32; l4 += 4) {
      f32x4 evv[2], sv[4];
#pragma unroll
      for (int n = 0; n < 2; ++n)
        evv[n] = *(const f32x4*)&ex_l[(col0 + n * 16) * 36 + l4];
#pragma unroll
      for (int j = 0; j < 4; ++j)
        sv[j] = *(const f32x4*)&ss_l[(row0 + m * 16 + j) * 36 + l4];
#pragma unroll
      for (int j = 0; j < 4; ++j)
#pragma unroll
        for (int n = 0; n < 2; ++n) {
          ssum[j][n] += fabsf(sv[j][0] - evv[n][0]) + fabsf(sv[j][1] - evv[n][1]) +
                        fabsf(sv[j][2] - evv[n][2]) + fabsf(sv[j][3] - evv[n][3]);
        }
    }
#pragma unroll
    for (int j = 0; j < 4; ++j) {
      int rloc = row0 + m * 16 + j;
      float cmv = cm_l[rloc];
#pragma unroll
      for (int n = 0; n < 2; ++n) {
        int cloc = col0 + n * 16;
        int cg = bcol + cloc;
        float tria = fminf(fmaxf(0.5f + 0.5f * acc1[m][n][j], EPS), 1.0f);
        float hier = fminf(fmaxf(0.5f + 0.25f * acc2[m][n][j], EPS), 1.0f);
        float sc = fminf(fmaxf(1.0f - ssum[j][n] * (1.0f / 31.0f), EPS), 1.0f);
        float d = cmv - pr_l[cloc];
        float cc = __expf(d * d * -10.0f) + 1e-8f;
        cc = fminf(fmaxf(cc, EPS), 1.0f);
        float p = tria * sc * cc * hier;
        if (cg < C_DIM)
          out[(size_t)(brow + rloc) * C_DIM + cg] = sqrtf(sqrtf(p));
      }
    }
  }
}

extern "C" void kernel_launch(void* const* d_in, const int* in_sizes, int n_in,
                              void* d_out, int out_size, void* d_ws, size_t ws_size,
                              hipStream_t stream) {
  (void)in_sizes; (void)n_in; (void)out_size; (void)ws_size;
  const float* pe = (const float*)d_in[0];     // B x L x F
  const float* cm = (const float*)d_in[1];     // B
  const float* sig = (const float*)d_in[2];    // C x L x F
  const float* proto = (const float*)d_in[3];  // C
  const float* lr = (const float*)d_in[4];     // C x L
  float* out = (float*)d_out;
  char* ws = (char*)d_ws;

  __hip_bfloat16* wsig = (__hip_bfloat16*)(ws);               // CP*2048*2 = 4 MiB
  __hip_bfloat16* pen = (__hip_bfloat16*)(ws + 4194304);      // B*2048*2 = 16 MiB
  __hip_bfloat16* elb = (__hip_bfloat16*)(ws + 20971520);     // B*128*2  = 1 MiB
  __hip_bfloat16* elc = (__hip_bfloat16*)(ws + 22020096);     // CP*128*2 = 256 KiB
  float* ssb = (float*)(ws + 22282240);                       // B*32*4   = 512 KiB
  float* expd = (float*)(ws + 22806528);                      // CP*32*4  = 128 KiB

  prep_all<<<(CP + B_DIM) / 4, 256, 0, stream>>>(sig, lr, pe, wsig, expd, elc, pen, ssb, elb);
  dim3 grid(B_DIM / 64, CP / 64);
  basin_main<<<grid, 256, 0, stream>>>(pen, wsig, elb, elc, ssb, expd, cm, proto, out);
}

// Round 10
// 85.533 us; speedup vs baseline: 2.1531x; 2.1531x over previous
//
#include <hip/hip_runtime.h>
#include <hip/hip_bf16.h>

typedef float f32x4 __attribute__((ext_vector_type(4)));
typedef short bf16x8 __attribute__((ext_vector_type(8)));

#define B_DIM 4096
#define C_DIM 1000
#define CP 1024
#define K1 2048
#define EPS 1e-6f

__device__ __forceinline__ float wsum(float v) {
#pragma unroll
  for (int o = 32; o > 0; o >>= 1) v += __shfl_xor(v, o, 64);
  return v;
}
__device__ __forceinline__ float wmax(float v) {
#pragma unroll
  for (int o = 32; o > 0; o >>= 1) v = fmaxf(v, __shfl_xor(v, o, 64));
  return v;
}

__device__ __forceinline__ void load_lds16(const void* g, void* l) {
  __builtin_amdgcn_global_load_lds(
      (const __attribute__((address_space(1))) unsigned int*)g,
      (__attribute__((address_space(3))) unsigned int*)l, 16, 0, 0);
}

// ---- merged prep: 4 units/block (256 thr). units [0,CP)=class, [CP,CP+B)=b ----
__global__ void prep_all(const float* __restrict__ sig,
                         const float* __restrict__ lr,
                         const float* __restrict__ pe,
                         __hip_bfloat16* __restrict__ wsig,
                         float* __restrict__ expd,
                         __hip_bfloat16* __restrict__ elc,
                         __hip_bfloat16* __restrict__ pen,
                         float* __restrict__ ssb,
                         __hip_bfloat16* __restrict__ elb) {
  const int t = threadIdx.x & 63;
  const int unit = blockIdx.x * 4 + (threadIdx.x >> 6);
  if (unit < CP) {
    const int c = unit;
    if (c >= C_DIM) {  // zero padding rows so the GEMM reads clean zeros
      for (int i = t; i < K1; i += 64) wsig[(size_t)c * K1 + i] = __float2bfloat16(0.f);
      if (t < 32) expd[c * 32 + t] = 0.f;
      elc[(size_t)c * 128 + t] = __float2bfloat16(0.f);
      elc[(size_t)c * 128 + 64 + t] = __float2bfloat16(0.f);
      return;
    }
    float lv = (t < 32) ? lr[c * 32 + t] : -3.0e38f;
    float mx = wmax(lv);
    float ev = (t < 32) ? expf(lv - mx) : 0.f;
    float sden = wsum(ev);
    float res = ev / sden;
    if (t < 31) {
      float d = lr[c * 32 + t] - lr[c * 32 + t + 1];
      expd[c * 32 + t] = 1.f / (1.f + expf(-d));
    } else if (t == 31) {
      expd[c * 32 + 31] = 0.f;
    }
    float es = 0.f, ls = 0.f;
    for (int l = 0; l < 32; ++l) {
      float s = sig[((size_t)c * 32 + l) * 64 + t];
      float nrm = fmaxf(sqrtf(wsum(s * s)), 1e-12f);
      float resl = __shfl(res, l, 64);
      wsig[((size_t)c * 32 + l) * 64 + t] = __float2bfloat16(s / nrm * resl);
      if (l < 16) es += s; else ls += s;
    }
    es *= (1.f / 16.f); ls *= (1.f / 16.f);
    float en = fmaxf(sqrtf(wsum(es * es)), 1e-12f);
    float ln2 = fmaxf(sqrtf(wsum(ls * ls)), 1e-12f);
    elc[(size_t)c * 128 + t] = __float2bfloat16(es / en);
    elc[(size_t)c * 128 + 64 + t] = __float2bfloat16(ls / ln2);
  } else {
    const int b = unit - CP;
    float v[32];
#pragma unroll
    for (int l = 0; l < 32; ++l) v[l] = pe[((size_t)b * 32 + l) * 64 + t];
    float nrm[32];
#pragma unroll
    for (int l = 0; l < 32; ++l) nrm[l] = sqrtf(wsum(v[l] * v[l]));
#pragma unroll
    for (int l = 0; l < 32; ++l)
      pen[((size_t)b * 32 + l) * 64 + t] = __float2bfloat16(v[l] / fmaxf(nrm[l], 1e-12f));
#pragma unroll
    for (int l = 0; l < 31; ++l) {
      float dot = wsum(v[l] * v[l + 1]);
      float cosv = dot / (fmaxf(nrm[l], 1e-8f) * fmaxf(nrm[l + 1], 1e-8f));
      if (t == 0) ssb[(size_t)b * 32 + l] = (cosv + 1.0f) * 0.5f;
    }
    if (t == 0) ssb[(size_t)b * 32 + 31] = 0.0f;
    float es = 0.f, ls = 0.f;
#pragma unroll
    for (int l = 0; l < 16; ++l) es += v[l];
#pragma unroll
    for (int l = 16; l < 32; ++l) ls += v[l];
    es *= (1.f / 16.f); ls *= (1.f / 16.f);
    float en = fmaxf(sqrtf(wsum(es * es)), 1e-12f);
    float ln2 = fmaxf(sqrtf(wsum(ls * ls)), 1e-12f);
    elb[(size_t)b * 128 + t] = __float2bfloat16(es / en);
    elb[(size_t)b * 128 + 64 + t] = __float2bfloat16(ls / ln2);
  }
}

// ---- main fused: 64x64 tile, 4 waves (32x32 each), BK=64, 2-buf ----
// VGPR law (R6..R9): launch_bounds 2nd arg w (waves/EU) caps arch VGPRs at
// ~256/w. This kernel needs ~124 -> w MUST be 2. w=4 => 64-VGPR cap => scratch
// spills => FETCH/WRITE x8 (R6/R7/R9). Runtime residency still reaches
// 4 blocks/CU (LDS 32KB, VGPR 124).
__global__ __launch_bounds__(256, 2)
void basin_main(const __hip_bfloat16* __restrict__ pen,
                const __hip_bfloat16* __restrict__ wsig,
                const __hip_bfloat16* __restrict__ elb,
                const __hip_bfloat16* __restrict__ elc,
                const float* __restrict__ ssb,
                const float* __restrict__ expd,
                const float* __restrict__ cm,
                const float* __restrict__ proto,
                float* __restrict__ out) {
  __shared__ __align__(16) char smem[32768];  // 2 x (A 8KB + B 8KB)
  const int t = threadIdx.x;
  const int lane = t & 63;
  const int w = t >> 6;                // 0..3
  const int wm = w >> 1, wn = w & 1;   // 2M x 2N waves, each 32x32
  const int brow = blockIdx.x * 64;
  const int bcol = blockIdx.y * 64;
  // staging: 8 threads per 128B row, 256 thr = 32 rows/inst; 2 insts per panel.
  const int srow = t >> 3;                          // 0..31
  const int selem = (((t & 7) ^ (srow & 7)) << 3);  // pre-swizzled source elem
  const int l15 = lane & 15;
  const int gq = lane >> 4;                         // quarter 0..3

  // per-lane ds_read byte offsets (loop-invariant; static-indexed)
  int offA[2][2], offB[2][2];
#pragma unroll
  for (int m = 0; m < 2; ++m)
#pragma unroll
    for (int kk = 0; kk < 2; ++kk) {
      int rowa = wm * 32 + m * 16 + l15;
      int rowb = wn * 32 + m * 16 + l15;
      int g = kk * 4 + gq;
      offA[m][kk] = rowa * 128 + ((g ^ (rowa & 7)) << 4);
      offB[m][kk] = rowb * 128 + ((g ^ (rowb & 7)) << 4);
    }

  f32x4 acc1[2][2] = {};
  f32x4 acc2[2][2] = {};

// buffer BI is a LITERAL. A at BI*16384, B at BI*16384+8192 (8KB each).
#define STAGE_T(kt, BI)                                                                   \
  do {                                                                                    \
    load_lds16(pen + (size_t)(brow + srow) * K1 + (kt) * 64 + selem,                      \
               smem + (BI) * 16384 + t * 16);                                             \
    load_lds16(pen + (size_t)(brow + 32 + srow) * K1 + (kt) * 64 + selem,                 \
               smem + (BI) * 16384 + 4096 + t * 16);                                      \
    load_lds16(wsig + (size_t)(bcol + srow) * K1 + (kt) * 64 + selem,                     \
               smem + (BI) * 16384 + 8192 + t * 16);                                      \
    load_lds16(wsig + (size_t)(bcol + 32 + srow) * K1 + (kt) * 64 + selem,                \
               smem + (BI) * 16384 + 12288 + t * 16);                                     \
  } while (0)

#define STAGE_H(kt, BI)                                                                   \
  do {                                                                                    \
    load_lds16(elb + (size_t)(brow + srow) * 128 + (kt) * 64 + selem,                     \
               smem + (BI) * 16384 + t * 16);                                             \
    load_lds16(elb + (size_t)(brow + 32 + srow) * 128 + (kt) * 64 + selem,                \
               smem + (BI) * 16384 + 4096 + t * 16);                                      \
    load_lds16(elc + (size_t)(bcol + srow) * 128 + (kt) * 64 + selem,                     \
               smem + (BI) * 16384 + 8192 + t * 16);                                      \
    load_lds16(elc + (size_t)(bcol + 32 + srow) * 128 + (kt) * 64 + selem,                \
               smem + (BI) * 16384 + 12288 + t * 16);                                     \
  } while (0)

#define COMPUTE(ACC, BI)                                                                  \
  do {                                                                                    \
    _Pragma("unroll") for (int kk = 0; kk < 2; ++kk) {                                    \
      bf16x8 af[2], bg[2];                                                                \
      af[0] = *(const bf16x8*)(smem + (BI) * 16384 + offA[0][kk]);                        \
      af[1] = *(const bf16x8*)(smem + (BI) * 16384 + offA[1][kk]);                        \
      bg[0] = *(const bf16x8*)(smem + (BI) * 16384 + 8192 + offB[0][kk]);                 \
      bg[1] = *(const bf16x8*)(smem + (BI) * 16384 + 8192 + offB[1][kk]);                 \
      _Pragma("unroll") for (int m = 0; m < 2; ++m)                                       \
        _Pragma("unroll") for (int n = 0; n < 2; ++n)                                     \
          ACC[m][n] = __builtin_amdgcn_mfma_f32_16x16x32_bf16(af[m], bg[n], ACC[m][n], 0, 0, 0); \
    }                                                                                     \
  } while (0)

#define KSTEP(kt, BI, OTHER)                                                              \
  do {                                                                                    \
    asm volatile("s_waitcnt vmcnt(0)" ::: "memory"); /* stage(kt) landed */               \
    __builtin_amdgcn_s_barrier();                    /* all waves: prev reads done */     \
    __builtin_amdgcn_sched_barrier(0);                                                    \
    if ((kt) + 1 < 32) STAGE_T((kt) + 1, OTHER);     /* issue next before compute */      \
    COMPUTE(acc1, BI);                                                                    \
  } while (0)

  // ---- triadic GEMM: K=2048, 32 steps of BK=64, dbuf, unroll x2 ----
  STAGE_T(0, 0);
  for (int kt = 0; kt < 32; kt += 2) {
    KSTEP(kt, 0, 1);
    KSTEP(kt + 1, 1, 0);
  }
  __syncthreads();  // everyone done with triadic reads

  // ---- hier GEMM: K=128 = 2 steps ----
  STAGE_H(0, 0);
  STAGE_H(1, 1);
  asm volatile("s_waitcnt vmcnt(4)" ::: "memory");  // stage_h(0) landed
  __builtin_amdgcn_s_barrier();
  __builtin_amdgcn_sched_barrier(0);
  COMPUTE(acc2, 0);
  asm volatile("s_waitcnt vmcnt(0)" ::: "memory");
  __builtin_amdgcn_s_barrier();
  __builtin_amdgcn_sched_barrier(0);
  COMPUTE(acc2, 1);
  __syncthreads();  // done reading before epilogue overwrites smem

  // ---- epilogue: stage ss/exp rows + cantor scalars in LDS ----
  float* ss_l = (float*)smem;            // [64][36] padded stride (9216B)
  float* ex_l = (float*)(smem + 9216);   // [64][36]
  float* cm_l = (float*)(smem + 18432);  // [64]
  float* pr_l = (float*)(smem + 18688);  // [64]
  for (int i = t; i < 2048; i += 256) {
    int r = i >> 5, l = i & 31;
    ss_l[r * 36 + l] = ssb[(size_t)(brow + r) * 32 + l];
    ex_l[r * 36 + l] = expd[(size_t)(bcol + r) * 32 + l];
  }
  if (t < 64) cm_l[t] = cm[brow + t];
  else if (t < 128) pr_l[t - 64] = (bcol + t - 64 < C_DIM) ? proto[bcol + t - 64] : 0.f;
  __syncthreads();

  const int col0 = wn * 32 + l15;
  const int row0 = wm * 32 + (gq << 2);
#pragma unroll
  for (int m = 0; m < 2; ++m) {
    float ssum[4][2];
#pragma unroll
    for (int j = 0; j < 4; ++j)
#pragma unroll
      for (int n = 0; n < 2; ++n) ssum[j][n] = 0.f;
#pragma unroll
    for (int l4 = 0; l4 < 32; l4 += 4) {
      f32x4 evv[2], sv[4];
#pragma unroll
      for (int n = 0; n < 2; ++n)
        evv[n] = *(const f32x4*)&ex_l[(col0 + n * 16) * 36 + l4];
#pragma unroll
      for (int j = 0; j < 4; ++j)
        sv[j] = *(const f32x4*)&ss_l[(row0 + m * 16 + j) * 36 + l4];
#pragma unroll
      for (int j = 0; j < 4; ++j)
#pragma unroll
        for (int n = 0; n < 2; ++n) {
          ssum[j][n] += fabsf(sv[j][0] - evv[n][0]) + fabsf(sv[j][1] - evv[n][1]) +
                        fabsf(sv[j][2] - evv[n][2]) + fabsf(sv[j][3] - evv[n][3]);
        }
    }
#pragma unroll
    for (int j = 0; j < 4; ++j) {
      int rloc = row0 + m * 16 + j;
      float cmv = cm_l[rloc];
#pragma unroll
      for (int n = 0; n < 2; ++n) {
        int cloc = col0 + n * 16;
        int cg = bcol + cloc;
        float tria = fminf(fmaxf(0.5f + 0.5f * acc1[m][n][j], EPS), 1.0f);
        float hier = fminf(fmaxf(0.5f + 0.25f * acc2[m][n][j], EPS), 1.0f);
        float sc = fminf(fmaxf(1.0f - ssum[j][n] * (1.0f / 31.0f), EPS), 1.0f);
        float d = cmv - pr_l[cloc];
        float cc = __expf(d * d * -10.0f) + 1e-8f;
        cc = fminf(fmaxf(cc, EPS), 1.0f);
        float p = tria * sc * cc * hier;
        if (cg < C_DIM)
          out[(size_t)(brow + rloc) * C_DIM + cg] = sqrtf(sqrtf(p));
      }
    }
  }
}

extern "C" void kernel_launch(void* const* d_in, const int* in_sizes, int n_in,
                              void* d_out, int out_size, void* d_ws, size_t ws_size,
                              hipStream_t stream) {
  (void)in_sizes; (void)n_in; (void)out_size; (void)ws_size;
  const float* pe = (const float*)d_in[0];     // B x L x F
  const float* cm = (const float*)d_in[1];     // B
  const float* sig = (const float*)d_in[2];    // C x L x F
  const float* proto = (const float*)d_in[3];  // C
  const float* lr = (const float*)d_in[4];     // C x L
  float* out = (float*)d_out;
  char* ws = (char*)d_ws;

  __hip_bfloat16* wsig = (__hip_bfloat16*)(ws);               // CP*2048*2 = 4 MiB
  __hip_bfloat16* pen = (__hip_bfloat16*)(ws + 4194304);      // B*2048*2 = 16 MiB
  __hip_bfloat16* elb = (__hip_bfloat16*)(ws + 20971520);     // B*128*2  = 1 MiB
  __hip_bfloat16* elc = (__hip_bfloat16*)(ws + 22020096);     // CP*128*2 = 256 KiB
  float* ssb = (float*)(ws + 22282240);                       // B*32*4   = 512 KiB
  float* expd = (float*)(ws + 22806528);                      // CP*32*4  = 128 KiB

  prep_all<<<(CP + B_DIM) / 4, 256, 0, stream>>>(sig, lr, pe, wsig, expd, elc, pen, ssb, elb);
  dim3 grid(B_DIM / 64, CP / 64);
  basin_main<<<grid, 256, 0, stream>>>(pen, wsig, elb, elc, ssb, expd, cm, proto, out);
}

// Round 11
// 72.719 us; speedup vs baseline: 2.5325x; 1.1762x over previous
//
#include <hip/hip_runtime.h>
#include <hip/hip_bf16.h>

typedef float f32x4 __attribute__((ext_vector_type(4)));
typedef short bf16x8 __attribute__((ext_vector_type(8)));

#define B_DIM 4096
#define C_DIM 1000
#define CP 1024
#define K1 2048
#define EPS 1e-6f

__device__ __forceinline__ float wsum(float v) {
#pragma unroll
  for (int o = 32; o > 0; o >>= 1) v += __shfl_xor(v, o, 64);
  return v;
}
__device__ __forceinline__ float wmax(float v) {
#pragma unroll
  for (int o = 32; o > 0; o >>= 1) v = fmaxf(v, __shfl_xor(v, o, 64));
  return v;
}

__device__ __forceinline__ void load_lds16(const void* g, void* l) {
  __builtin_amdgcn_global_load_lds(
      (const __attribute__((address_space(1))) unsigned int*)g,
      (__attribute__((address_space(3))) unsigned int*)l, 16, 0, 0);
}

// ---- merged prep v2: row-per-lane in-register reductions via LDS transpose.
// R10 analysis: old prep spent ~390 serial ds_swizzle/unit (63 wsums). Now:
// stage unit [32][72] f32 in LDS, lane l reduces row l with 16 f32x4 FMAs
// (no shuffles), write phase back in F-layout with LDS broadcasts.
// Blocks are homogeneous: blocks 0..255 class units, 256..1279 pe units.
__global__ void prep_all(const float* __restrict__ sig,
                         const float* __restrict__ lr,
                         const float* __restrict__ pe,
                         __hip_bfloat16* __restrict__ wsig,
                         float* __restrict__ expd,
                         __hip_bfloat16* __restrict__ elc,
                         __hip_bfloat16* __restrict__ pen,
                         float* __restrict__ ssb,
                         __hip_bfloat16* __restrict__ elb) {
  __shared__ float LW[4][2304];  // per wave: [32][72] padded f32
  __shared__ float AUX[4][32];   // per wave: per-row multiplier
  const int w = threadIdx.x >> 6;
  const int t = threadIdx.x & 63;
  const int unit = blockIdx.x * 4 + w;
  const bool isClass = unit < CP;
  const int c = unit;
  const int b = unit - CP;
  const bool pad = isClass && (c >= C_DIM);
  const float* src = isClass ? (sig + (size_t)c * K1) : (pe + (size_t)b * K1);

  // ---- stage 2048 f32, coalesced f32x4 ----
#pragma unroll
  for (int i = 0; i < 8; ++i) {
    int o = i * 256 + t * 4;
    f32x4 v = {0.f, 0.f, 0.f, 0.f};
    if (!pad) v = *(const f32x4*)(src + o);
    *(f32x4*)&LW[w][(o >> 6) * 72 + (o & 63)] = v;
  }
  __syncthreads();

  // ---- per-row reductions (lanes 0..31 = rows) + class softmax/expd ----
  if (isClass) {
    float lv = (t < 32 && !pad) ? lr[c * 32 + t] : -3.0e38f;
    float mx = wmax(lv);
    float ev = (t < 32 && !pad) ? expf(lv - mx) : 0.f;
    float sden = wsum(ev);
    float res = pad ? 0.f : ev / sden;
    float lvn = __shfl_down(lv, 1, 64);
    if (t < 31) {
      expd[c * 32 + t] = pad ? 0.f : 1.f / (1.f + expf(-(lv - lvn)));
    } else if (t == 31) {
      expd[c * 32 + 31] = 0.f;
    }
    if (t < 32) {
      f32x4 sq = {0.f, 0.f, 0.f, 0.f};
#pragma unroll
      for (int i = 0; i < 16; ++i) {
        f32x4 v = *(const f32x4*)&LW[w][t * 72 + i * 4];
        sq += v * v;
      }
      float s = sq[0] + sq[1] + sq[2] + sq[3];
      float inv = 1.f / fmaxf(sqrtf(s), 1e-12f);
      AUX[w][t] = inv * res;  // wsig multiplier
    }
  } else {
    if (t < 32) {
      f32x4 sq = {0.f, 0.f, 0.f, 0.f}, dt = {0.f, 0.f, 0.f, 0.f};
      const int tn = (t < 31) ? t + 1 : t;
#pragma unroll
      for (int i = 0; i < 16; ++i) {
        f32x4 v = *(const f32x4*)&LW[w][t * 72 + i * 4];
        f32x4 vn = *(const f32x4*)&LW[w][tn * 72 + i * 4];
        sq += v * v;
        dt += v * vn;
      }
      float s = sq[0] + sq[1] + sq[2] + sq[3];
      float d = dt[0] + dt[1] + dt[2] + dt[3];
      float nrm = sqrtf(s);
      AUX[w][t] = 1.f / fmaxf(nrm, 1e-12f);  // pen multiplier
      float nn = __shfl_down(nrm, 1, 64);
      if (t < 31)
        ssb[(size_t)b * 32 + t] =
            (d / (fmaxf(nrm, 1e-8f) * fmaxf(nn, 1e-8f)) + 1.f) * 0.5f;
      else
        ssb[(size_t)b * 32 + 31] = 0.f;
    }
  }
  __syncthreads();

  // ---- write phase: F-layout coalesced bf16 stores + early/late means ----
  __hip_bfloat16* dst = isClass ? (wsig + (size_t)c * K1) : (pen + (size_t)b * K1);
  float es = 0.f, ls = 0.f;
#pragma unroll
  for (int l = 0; l < 32; ++l) {
    float v = LW[w][l * 72 + t];
    float m = AUX[w][l];  // broadcast (uniform addr) = free
    dst[l * 64 + t] = __float2bfloat16(v * m);
    if (l < 16) es += v; else ls += v;
  }
  es *= (1.f / 16.f);
  ls *= (1.f / 16.f);
  float en = fmaxf(sqrtf(wsum(es * es)), 1e-12f);
  float ln2 = fmaxf(sqrtf(wsum(ls * ls)), 1e-12f);
  __hip_bfloat16* el = isClass ? (elc + (size_t)c * 128) : (elb + (size_t)b * 128);
  el[t] = __float2bfloat16(es / en);
  el[64 + t] = __float2bfloat16(ls / ln2);
}

// ---- main fused: 64x64 tile, 4 waves (32x32 each), BK=64, 2-buf ----
// VGPR law (R6..R9): launch_bounds 2nd arg w (waves/EU) caps arch VGPRs at
// ~256/w. This kernel needs ~124 -> w MUST be 2. w=4 => 64-VGPR cap => scratch
// spills => FETCH/WRITE x8 (R6/R7/R9).
__global__ __launch_bounds__(256, 2)
void basin_main(const __hip_bfloat16* __restrict__ pen,
                const __hip_bfloat16* __restrict__ wsig,
                const __hip_bfloat16* __restrict__ elb,
                const __hip_bfloat16* __restrict__ elc,
                const float* __restrict__ ssb,
                const float* __restrict__ expd,
                const float* __restrict__ cm,
                const float* __restrict__ proto,
                float* __restrict__ out) {
  __shared__ __align__(16) char smem[32768];  // 2 x (A 8KB + B 8KB)
  const int t = threadIdx.x;
  const int lane = t & 63;
  const int w = t >> 6;                // 0..3
  const int wm = w >> 1, wn = w & 1;   // 2M x 2N waves, each 32x32
  const int brow = blockIdx.x * 64;
  const int bcol = blockIdx.y * 64;
  // staging: 8 threads per 128B row, 256 thr = 32 rows/inst; 2 insts per panel.
  const int srow = t >> 3;                          // 0..31
  const int selem = (((t & 7) ^ (srow & 7)) << 3);  // pre-swizzled source elem
  const int l15 = lane & 15;
  const int gq = lane >> 4;                         // quarter 0..3

  // per-lane ds_read byte offsets (loop-invariant; static-indexed)
  int offA[2][2], offB[2][2];
#pragma unroll
  for (int m = 0; m < 2; ++m)
#pragma unroll
    for (int kk = 0; kk < 2; ++kk) {
      int rowa = wm * 32 + m * 16 + l15;
      int rowb = wn * 32 + m * 16 + l15;
      int g = kk * 4 + gq;
      offA[m][kk] = rowa * 128 + ((g ^ (rowa & 7)) << 4);
      offB[m][kk] = rowb * 128 + ((g ^ (rowb & 7)) << 4);
    }

  f32x4 acc1[2][2] = {};
  f32x4 acc2[2][2] = {};

// buffer BI is a LITERAL. A at BI*16384, B at BI*16384+8192 (8KB each).
#define STAGE_T(kt, BI)                                                                   \
  do {                                                                                    \
    load_lds16(pen + (size_t)(brow + srow) * K1 + (kt) * 64 + selem,                      \
               smem + (BI) * 16384 + t * 16);                                             \
    load_lds16(pen + (size_t)(brow + 32 + srow) * K1 + (kt) * 64 + selem,                 \
               smem + (BI) * 16384 + 4096 + t * 16);                                      \
    load_lds16(wsig + (size_t)(bcol + srow) * K1 + (kt) * 64 + selem,                     \
               smem + (BI) * 16384 + 8192 + t * 16);                                      \
    load_lds16(wsig + (size_t)(bcol + 32 + srow) * K1 + (kt) * 64 + selem,                \
               smem + (BI) * 16384 + 12288 + t * 16);                                     \
  } while (0)

#define STAGE_H(kt, BI)                                                                   \
  do {                                                                                    \
    load_lds16(elb + (size_t)(brow + srow) * 128 + (kt) * 64 + selem,                     \
               smem + (BI) * 16384 + t * 16);                                             \
    load_lds16(elb + (size_t)(brow + 32 + srow) * 128 + (kt) * 64 + selem,                \
               smem + (BI) * 16384 + 4096 + t * 16);                                      \
    load_lds16(elc + (size_t)(bcol + srow) * 128 + (kt) * 64 + selem,                     \
               smem + (BI) * 16384 + 8192 + t * 16);                                      \
    load_lds16(elc + (size_t)(bcol + 32 + srow) * 128 + (kt) * 64 + selem,                \
               smem + (BI) * 16384 + 12288 + t * 16);                                     \
  } while (0)

#define COMPUTE(ACC, BI)                                                                  \
  do {                                                                                    \
    _Pragma("unroll") for (int kk = 0; kk < 2; ++kk) {                                    \
      bf16x8 af[2], bg[2];                                                                \
      af[0] = *(const bf16x8*)(smem + (BI) * 16384 + offA[0][kk]);                        \
      af[1] = *(const bf16x8*)(smem + (BI) * 16384 + offA[1][kk]);                        \
      bg[0] = *(const bf16x8*)(smem + (BI) * 16384 + 8192 + offB[0][kk]);                 \
      bg[1] = *(const bf16x8*)(smem + (BI) * 16384 + 8192 + offB[1][kk]);                 \
      _Pragma("unroll") for (int m = 0; m < 2; ++m)                                       \
        _Pragma("unroll") for (int n = 0; n < 2; ++n)                                     \
          ACC[m][n] = __builtin_amdgcn_mfma_f32_16x16x32_bf16(af[m], bg[n], ACC[m][n], 0, 0, 0); \
    }                                                                                     \
  } while (0)

#define KSTEP(kt, BI, OTHER)                                                              \
  do {                                                                                    \
    asm volatile("s_waitcnt vmcnt(0)" ::: "memory"); /* stage(kt) landed */               \
    __builtin_amdgcn_s_barrier();                    /* all waves: prev reads done */     \
    __builtin_amdgcn_sched_barrier(0);                                                    \
    if ((kt) + 1 < 32) STAGE_T((kt) + 1, OTHER);     /* issue next before compute */      \
    COMPUTE(acc1, BI);                                                                    \
  } while (0)

  // ---- triadic GEMM: K=2048, 32 steps of BK=64, dbuf, unroll x2 ----
  STAGE_T(0, 0);
  for (int kt = 0; kt < 32; kt += 2) {
    KSTEP(kt, 0, 1);
    KSTEP(kt + 1, 1, 0);
  }
  __syncthreads();  // everyone done with triadic reads

  // ---- hier GEMM: K=128 = 2 steps ----
  STAGE_H(0, 0);
  STAGE_H(1, 1);
  asm volatile("s_waitcnt vmcnt(4)" ::: "memory");  // stage_h(0) landed
  __builtin_amdgcn_s_barrier();
  __builtin_amdgcn_sched_barrier(0);
  COMPUTE(acc2, 0);
  asm volatile("s_waitcnt vmcnt(0)" ::: "memory");
  __builtin_amdgcn_s_barrier();
  __builtin_amdgcn_sched_barrier(0);
  COMPUTE(acc2, 1);
  __syncthreads();  // done reading before epilogue overwrites smem

  // ---- epilogue: stage ss/exp rows + cantor scalars in LDS ----
  float* ss_l = (float*)smem;            // [64][36] padded stride (9216B)
  float* ex_l = (float*)(smem + 9216);   // [64][36]
  float* cm_l = (float*)(smem + 18432);  // [64]
  float* pr_l = (float*)(smem + 18688);  // [64]
  for (int i = t; i < 2048; i += 256) {
    int r = i >> 5, l = i & 31;
    ss_l[r * 36 + l] = ssb[(size_t)(brow + r) * 32 + l];
    ex_l[r * 36 + l] = expd[(size_t)(bcol + r) * 32 + l];
  }
  if (t < 64) cm_l[t] = cm[brow + t];
  else if (t < 128) pr_l[t - 64] = (bcol + t - 64 < C_DIM) ? proto[bcol + t - 64] : 0.f;
  __syncthreads();

  const int col0 = wn * 32 + l15;
  const int row0 = wm * 32 + (gq << 2);
#pragma unroll
  for (int m = 0; m < 2; ++m) {
    float ssum[4][2];
#pragma unroll
    for (int j = 0; j < 4; ++j)
#pragma unroll
      for (int n = 0; n < 2; ++n) ssum[j][n] = 0.f;
#pragma unroll
    for (int l4 = 0; l4 < 32; l4 += 4) {
      f32x4 evv[2], sv[4];
#pragma unroll
      for (int n = 0; n < 2; ++n)
        evv[n] = *(const f32x4*)&ex_l[(col0 + n * 16) * 36 + l4];
#pragma unroll
      for (int j = 0; j < 4; ++j)
        sv[j] = *(const f32x4*)&ss_l[(row0 + m * 16 + j) * 36 + l4];
#pragma unroll
      for (int j = 0; j < 4; ++j)
#pragma unroll
        for (int n = 0; n < 2; ++n) {
          ssum[j][n] += fabsf(sv[j][0] - evv[n][0]) + fabsf(sv[j][1] - evv[n][1]) +
                        fabsf(sv[j][2] - evv[n][2]) + fabsf(sv[j][3] - evv[n][3]);
        }
    }
#pragma unroll
    for (int j = 0; j < 4; ++j) {
      int rloc = row0 + m * 16 + j;
      float cmv = cm_l[rloc];
#pragma unroll
      for (int n = 0; n < 2; ++n) {
        int cloc = col0 + n * 16;
        int cg = bcol + cloc;
        float tria = fminf(fmaxf(0.5f + 0.5f * acc1[m][n][j], EPS), 1.0f);
        float hier = fminf(fmaxf(0.5f + 0.25f * acc2[m][n][j], EPS), 1.0f);
        float sc = fminf(fmaxf(1.0f - ssum[j][n] * (1.0f / 31.0f), EPS), 1.0f);
        float d = cmv - pr_l[cloc];
        float cc = __expf(d * d * -10.0f) + 1e-8f;
        cc = fminf(fmaxf(cc, EPS), 1.0f);
        float p = tria * sc * cc * hier;
        if (cg < C_DIM)
          out[(size_t)(brow + rloc) * C_DIM + cg] = sqrtf(sqrtf(p));
      }
    }
  }
}

extern "C" void kernel_launch(void* const* d_in, const int* in_sizes, int n_in,
                              void* d_out, int out_size, void* d_ws, size_t ws_size,
                              hipStream_t stream) {
  (void)in_sizes; (void)n_in; (void)out_size; (void)ws_size;
  const float* pe = (const float*)d_in[0];     // B x L x F
  const float* cm = (const float*)d_in[1];     // B
  const float* sig = (const float*)d_in[2];    // C x L x F
  const float* proto = (const float*)d_in[3];  // C
  const float* lr = (const float*)d_in[4];     // C x L
  float* out = (float*)d_out;
  char* ws = (char*)d_ws;

  __hip_bfloat16* wsig = (__hip_bfloat16*)(ws);               // CP*2048*2 = 4 MiB
  __hip_bfloat16* pen = (__hip_bfloat16*)(ws + 4194304);      // B*2048*2 = 16 MiB
  __hip_bfloat16* elb = (__hip_bfloat16*)(ws + 20971520);     // B*128*2  = 1 MiB
  __hip_bfloat16* elc = (__hip_bfloat16*)(ws + 22020096);     // CP*128*2 = 256 KiB
  float* ssb = (float*)(ws + 22282240);                       // B*32*4   = 512 KiB
  float* expd = (float*)(ws + 22806528);                      // CP*32*4  = 128 KiB

  prep_all<<<(CP + B_DIM) / 4, 256, 0, stream>>>(sig, lr, pe, wsig, expd, elc, pen, ssb, elb);
  dim3 grid(B_DIM / 64, CP / 64);
  basin_main<<<grid, 256, 0, stream>>>(pen, wsig, elb, elc, ssb, expd, cm, proto, out);
}

// Round 12
// 62.404 us; speedup vs baseline: 2.9511x; 1.1653x over previous
//
#include <hip/hip_runtime.h>
#include <hip/hip_bf16.h>

typedef float f32x4 __attribute__((ext_vector_type(4)));
typedef short bf16x8 __attribute__((ext_vector_type(8)));

#define B_DIM 4096
#define C_DIM 1000
#define CP 1024
#define K1 2048
#define EPS 1e-6f

__device__ __forceinline__ float wsum(float v) {
#pragma unroll
  for (int o = 32; o > 0; o >>= 1) v += __shfl_xor(v, o, 64);
  return v;
}
__device__ __forceinline__ float wmax(float v) {
#pragma unroll
  for (int o = 32; o > 0; o >>= 1) v = fmaxf(v, __shfl_xor(v, o, 64));
  return v;
}

__device__ __forceinline__ void load_lds16(const void* g, void* l) {
  __builtin_amdgcn_global_load_lds(
      (const __attribute__((address_space(1))) unsigned int*)g,
      (__attribute__((address_space(3))) unsigned int*)l, 16, 0, 0);
}

// ---- merged prep v2 (R11: 13.5us): row-per-lane reductions via LDS transpose.
__global__ void prep_all(const float* __restrict__ sig,
                         const float* __restrict__ lr,
                         const float* __restrict__ pe,
                         __hip_bfloat16* __restrict__ wsig,
                         float* __restrict__ expd,
                         __hip_bfloat16* __restrict__ elc,
                         __hip_bfloat16* __restrict__ pen,
                         float* __restrict__ ssb,
                         __hip_bfloat16* __restrict__ elb) {
  __shared__ float LW[4][2304];  // per wave: [32][72] padded f32
  __shared__ float AUX[4][32];   // per wave: per-row multiplier
  const int w = threadIdx.x >> 6;
  const int t = threadIdx.x & 63;
  const int unit = blockIdx.x * 4 + w;
  const bool isClass = unit < CP;
  const int c = unit;
  const int b = unit - CP;
  const bool pad = isClass && (c >= C_DIM);
  const float* src = isClass ? (sig + (size_t)c * K1) : (pe + (size_t)b * K1);

#pragma unroll
  for (int i = 0; i < 8; ++i) {
    int o = i * 256 + t * 4;
    f32x4 v = {0.f, 0.f, 0.f, 0.f};
    if (!pad) v = *(const f32x4*)(src + o);
    *(f32x4*)&LW[w][(o >> 6) * 72 + (o & 63)] = v;
  }
  __syncthreads();

  if (isClass) {
    float lv = (t < 32 && !pad) ? lr[c * 32 + t] : -3.0e38f;
    float mx = wmax(lv);
    float ev = (t < 32 && !pad) ? expf(lv - mx) : 0.f;
    float sden = wsum(ev);
    float res = pad ? 0.f : ev / sden;
    float lvn = __shfl_down(lv, 1, 64);
    if (t < 31) {
      expd[c * 32 + t] = pad ? 0.f : 1.f / (1.f + expf(-(lv - lvn)));
    } else if (t == 31) {
      expd[c * 32 + 31] = 0.f;
    }
    if (t < 32) {
      f32x4 sq = {0.f, 0.f, 0.f, 0.f};
#pragma unroll
      for (int i = 0; i < 16; ++i) {
        f32x4 v = *(const f32x4*)&LW[w][t * 72 + i * 4];
        sq += v * v;
      }
      float s = sq[0] + sq[1] + sq[2] + sq[3];
      float inv = 1.f / fmaxf(sqrtf(s), 1e-12f);
      AUX[w][t] = inv * res;
    }
  } else {
    if (t < 32) {
      f32x4 sq = {0.f, 0.f, 0.f, 0.f}, dt = {0.f, 0.f, 0.f, 0.f};
      const int tn = (t < 31) ? t + 1 : t;
#pragma unroll
      for (int i = 0; i < 16; ++i) {
        f32x4 v = *(const f32x4*)&LW[w][t * 72 + i * 4];
        f32x4 vn = *(const f32x4*)&LW[w][tn * 72 + i * 4];
        sq += v * v;
        dt += v * vn;
      }
      float s = sq[0] + sq[1] + sq[2] + sq[3];
      float d = dt[0] + dt[1] + dt[2] + dt[3];
      float nrm = sqrtf(s);
      AUX[w][t] = 1.f / fmaxf(nrm, 1e-12f);
      float nn = __shfl_down(nrm, 1, 64);
      if (t < 31)
        ssb[(size_t)b * 32 + t] =
            (d / (fmaxf(nrm, 1e-8f) * fmaxf(nn, 1e-8f)) + 1.f) * 0.5f;
      else
        ssb[(size_t)b * 32 + 31] = 0.f;
    }
  }
  __syncthreads();

  __hip_bfloat16* dst = isClass ? (wsig + (size_t)c * K1) : (pen + (size_t)b * K1);
  float es = 0.f, ls = 0.f;
#pragma unroll
  for (int l = 0; l < 32; ++l) {
    float v = LW[w][l * 72 + t];
    float m = AUX[w][l];
    dst[l * 64 + t] = __float2bfloat16(v * m);
    if (l < 16) es += v; else ls += v;
  }
  es *= (1.f / 16.f);
  ls *= (1.f / 16.f);
  float en = fmaxf(sqrtf(wsum(es * es)), 1e-12f);
  float ln2 = fmaxf(sqrtf(wsum(ls * ls)), 1e-12f);
  __hip_bfloat16* el = isClass ? (elc + (size_t)c * 128) : (elb + (size_t)b * 128);
  el[t] = __float2bfloat16(es / en);
  el[64 + t] = __float2bfloat16(ls / ln2);
}

// ---- main fused: 128x128 tile, 8 waves (64x32 each), BK=128, 2x64KB dbuf ----
// R11 diagnosis: staging path is BW-bound at ~9 TB/s chip-wide (Little's law
// consistent across R2..R10; every structure converged to ~59us). Lever is
// REUSE: 128x128 tile cuts staged traffic 512MB -> 256MB -> ~28us floor.
// Grid 256 = 1 blk/CU; depth-1 prefetch keeps 64KB/CU in flight (pipe full).
// VGPR law (R6..R9): launch_bounds w=2 only; w=4 => 64-VGPR cap => spills.
__global__ __launch_bounds__(512, 2)
void basin_main(const __hip_bfloat16* __restrict__ pen,
                const __hip_bfloat16* __restrict__ wsig,
                const __hip_bfloat16* __restrict__ elb,
                const __hip_bfloat16* __restrict__ elc,
                const float* __restrict__ ssb,
                const float* __restrict__ expd,
                const float* __restrict__ cm,
                const float* __restrict__ proto,
                float* __restrict__ out) {
  __shared__ __align__(16) char smem[131072];  // 2 x (A 32KB + B 32KB)
  const int t = threadIdx.x;
  const int lane = t & 63;
  const int w = t >> 6;               // 0..7
  const int wm = w >> 2, wn = w & 3;  // 2M x 4N waves, each 64x32
  const int brow = blockIdx.x * 128;
  const int bcol = blockIdx.y * 128;
  // staging: 16 threads per 256B row (BK=128). granule-XOR swizzle g^=row&15
  // (both sides, rule 21): read bank spread 16-way -> 2-way (free).
  const int srow16 = t >> 4;                          // 0..31
  const int sel = (((t & 15) ^ (srow16 & 15)) << 3);  // pre-swizzled src elem
  const int l15 = lane & 15;
  const int gq = lane >> 4;                           // 0..3

  // loop-invariant read offset pieces: row bytes + per-kk swizzled granule
  const int rowA = (wm * 64 + l15) << 8;
  const int rowB = ((wn * 32 + l15) << 8) + 32768;
  int xg[4];
#pragma unroll
  for (int kk = 0; kk < 4; ++kk) xg[kk] = (((kk * 4 + gq) ^ l15) << 4);

  f32x4 acc1[4][2] = {};
  f32x4 acc2[4][2] = {};

// BI literal. A at BI*65536, B at BI*65536+32768. 8 loads/thread/step (64KB).
#define STAGE_T(kt, BI)                                                                   \
  do {                                                                                    \
    _Pragma("unroll") for (int i = 0; i < 4; ++i) {                                       \
      load_lds16(pen + (size_t)(brow + i * 32 + srow16) * K1 + (kt) * 128 + sel,          \
                 smem + (BI) * 65536 + i * 8192 + t * 16);                                \
      load_lds16(wsig + (size_t)(bcol + i * 32 + srow16) * K1 + (kt) * 128 + sel,         \
                 smem + (BI) * 65536 + 32768 + i * 8192 + t * 16);                        \
    }                                                                                     \
  } while (0)

#define STAGE_H()                                                                         \
  do {                                                                                    \
    _Pragma("unroll") for (int i = 0; i < 4; ++i) {                                       \
      load_lds16(elb + (size_t)(brow + i * 32 + srow16) * 128 + sel,                      \
                 smem + i * 8192 + t * 16);                                               \
      load_lds16(elc + (size_t)(bcol + i * 32 + srow16) * 128 + sel,                      \
                 smem + 32768 + i * 8192 + t * 16);                                       \
    }                                                                                     \
  } while (0)

// per step: 4 kk x (6 ds_read_b128 + 8 MFMA) = 24 ds + 32 MFMA
#define COMPUTE(ACC, BI)                                                                  \
  do {                                                                                    \
    _Pragma("unroll") for (int kk = 0; kk < 4; ++kk) {                                    \
      bf16x8 af[4], bg[2];                                                                \
      _Pragma("unroll") for (int m = 0; m < 4; ++m)                                       \
          af[m] = *(const bf16x8*)(smem + (BI) * 65536 + rowA + m * 4096 + xg[kk]);       \
      _Pragma("unroll") for (int n = 0; n < 2; ++n)                                       \
          bg[n] = *(const bf16x8*)(smem + (BI) * 65536 + rowB + n * 4096 + xg[kk]);       \
      _Pragma("unroll") for (int m = 0; m < 4; ++m)                                       \
        _Pragma("unroll") for (int n = 0; n < 2; ++n)                                     \
          ACC[m][n] = __builtin_amdgcn_mfma_f32_16x16x32_bf16(af[m], bg[n], ACC[m][n], 0, 0, 0); \
    }                                                                                     \
  } while (0)

#define KSTEP(kt, BI, OTHER)                                                              \
  do {                                                                                    \
    asm volatile("s_waitcnt vmcnt(0)" ::: "memory"); /* stage(kt) landed */               \
    __builtin_amdgcn_s_barrier();                    /* all waves' loads + prev reads */  \
    __builtin_amdgcn_sched_barrier(0);                                                    \
    if ((kt) + 1 < 16) STAGE_T((kt) + 1, OTHER);     /* issue next before compute */      \
    COMPUTE(acc1, BI);                                                                    \
  } while (0)

  // ---- triadic GEMM: K=2048, 16 steps of BK=128 ----
  STAGE_T(0, 0);
  for (int kt = 0; kt < 16; kt += 2) {
    KSTEP(kt, 0, 1);
    KSTEP(kt + 1, 1, 0);
  }
  __syncthreads();

  // ---- hier GEMM: K=128 = one BK=128 step ----
  STAGE_H();
  asm volatile("s_waitcnt vmcnt(0)" ::: "memory");
  __builtin_amdgcn_s_barrier();
  __builtin_amdgcn_sched_barrier(0);
  COMPUTE(acc2, 0);
  __syncthreads();  // done reading before epilogue overwrites smem

  // ---- epilogue: stage ss/exp rows + cantor scalars in LDS ----
  float* ss_l = (float*)smem;            // [128][36] padded (18432B)
  float* ex_l = (float*)(smem + 18432);  // [128][36]
  float* cm_l = (float*)(smem + 36864);  // [128]
  float* pr_l = (float*)(smem + 37376);  // [128]
  for (int i = t; i < 4096; i += 512) {
    int r = i >> 5, l = i & 31;
    ss_l[r * 36 + l] = ssb[(size_t)(brow + r) * 32 + l];
    ex_l[r * 36 + l] = expd[(size_t)(bcol + r) * 32 + l];
  }
  if (t < 128) cm_l[t] = cm[brow + t];
  else if (t < 256) pr_l[t - 128] = (bcol + t - 128 < C_DIM) ? proto[bcol + t - 128] : 0.f;
  __syncthreads();

  const int col0 = wn * 32 + l15;
  const int row0 = wm * 64 + (gq << 2);
#pragma unroll
  for (int m = 0; m < 4; ++m) {
    float ssum[4][2];
#pragma unroll
    for (int j = 0; j < 4; ++j)
#pragma unroll
      for (int n = 0; n < 2; ++n) ssum[j][n] = 0.f;
#pragma unroll
    for (int l4 = 0; l4 < 32; l4 += 4) {
      f32x4 evv[2], sv[4];
#pragma unroll
      for (int n = 0; n < 2; ++n)
        evv[n] = *(const f32x4*)&ex_l[(col0 + n * 16) * 36 + l4];
#pragma unroll
      for (int j = 0; j < 4; ++j)
        sv[j] = *(const f32x4*)&ss_l[(row0 + m * 16 + j) * 36 + l4];
#pragma unroll
      for (int j = 0; j < 4; ++j)
#pragma unroll
        for (int n = 0; n < 2; ++n) {
          ssum[j][n] += fabsf(sv[j][0] - evv[n][0]) + fabsf(sv[j][1] - evv[n][1]) +
                        fabsf(sv[j][2] - evv[n][2]) + fabsf(sv[j][3] - evv[n][3]);
        }
    }
#pragma unroll
    for (int j = 0; j < 4; ++j) {
      int rloc = row0 + m * 16 + j;
      float cmv = cm_l[rloc];
#pragma unroll
      for (int n = 0; n < 2; ++n) {
        int cloc = col0 + n * 16;
        int cg = bcol + cloc;
        float tria = fminf(fmaxf(0.5f + 0.5f * acc1[m][n][j], EPS), 1.0f);
        float hier = fminf(fmaxf(0.5f + 0.25f * acc2[m][n][j], EPS), 1.0f);
        float sc = fminf(fmaxf(1.0f - ssum[j][n] * (1.0f / 31.0f), EPS), 1.0f);
        float d = cmv - pr_l[cloc];
        float cc = __expf(d * d * -10.0f) + 1e-8f;
        cc = fminf(fmaxf(cc, EPS), 1.0f);
        float p = tria * sc * cc * hier;
        if (cg < C_DIM)
          out[(size_t)(brow + rloc) * C_DIM + cg] = sqrtf(sqrtf(p));
      }
    }
  }
}

extern "C" void kernel_launch(void* const* d_in, const int* in_sizes, int n_in,
                              void* d_out, int out_size, void* d_ws, size_t ws_size,
                              hipStream_t stream) {
  (void)in_sizes; (void)n_in; (void)out_size; (void)ws_size;
  const float* pe = (const float*)d_in[0];     // B x L x F
  const float* cm = (const float*)d_in[1];     // B
  const float* sig = (const float*)d_in[2];    // C x L x F
  const float* proto = (const float*)d_in[3];  // C
  const float* lr = (const float*)d_in[4];     // C x L
  float* out = (float*)d_out;
  char* ws = (char*)d_ws;

  __hip_bfloat16* wsig = (__hip_bfloat16*)(ws);               // CP*2048*2 = 4 MiB
  __hip_bfloat16* pen = (__hip_bfloat16*)(ws + 4194304);      // B*2048*2 = 16 MiB
  __hip_bfloat16* elb = (__hip_bfloat16*)(ws + 20971520);     // B*128*2  = 1 MiB
  __hip_bfloat16* elc = (__hip_bfloat16*)(ws + 22020096);     // CP*128*2 = 256 KiB
  float* ssb = (float*)(ws + 22282240);                       // B*32*4   = 512 KiB
  float* expd = (float*)(ws + 22806528);                      // CP*32*4  = 128 KiB

  prep_all<<<(CP + B_DIM) / 4, 256, 0, stream>>>(sig, lr, pe, wsig, expd, elc, pen, ssb, elb);
  dim3 grid(B_DIM / 128, CP / 128);
  basin_main<<<grid, 512, 0, stream>>>(pen, wsig, elb, elc, ssb, expd, cm, proto, out);
}

// Round 13
// 59.103 us; speedup vs baseline: 3.1159x; 1.0559x over previous
//
#include <hip/hip_runtime.h>
#include <hip/hip_bf16.h>

typedef float f32x4 __attribute__((ext_vector_type(4)));
typedef short bf16x8 __attribute__((ext_vector_type(8)));

#define B_DIM 4096
#define C_DIM 1000
#define CP 1024
#define K1 2048
#define EPS 1e-6f

__device__ __forceinline__ float wsum(float v) {
#pragma unroll
  for (int o = 32; o > 0; o >>= 1) v += __shfl_xor(v, o, 64);
  return v;
}
__device__ __forceinline__ float wmax(float v) {
#pragma unroll
  for (int o = 32; o > 0; o >>= 1) v = fmaxf(v, __shfl_xor(v, o, 64));
  return v;
}

__device__ __forceinline__ void load_lds16(const void* g, void* l) {
  __builtin_amdgcn_global_load_lds(
      (const __attribute__((address_space(1))) unsigned int*)g,
      (__attribute__((address_space(3))) unsigned int*)l, 16, 0, 0);
}

// ---- merged prep v2 (R11: 13.5us): row-per-lane reductions via LDS transpose.
__global__ void prep_all(const float* __restrict__ sig,
                         const float* __restrict__ lr,
                         const float* __restrict__ pe,
                         __hip_bfloat16* __restrict__ wsig,
                         float* __restrict__ expd,
                         __hip_bfloat16* __restrict__ elc,
                         __hip_bfloat16* __restrict__ pen,
                         float* __restrict__ ssb,
                         __hip_bfloat16* __restrict__ elb) {
  __shared__ float LW[4][2304];  // per wave: [32][72] padded f32
  __shared__ float AUX[4][32];   // per wave: per-row multiplier
  const int w = threadIdx.x >> 6;
  const int t = threadIdx.x & 63;
  const int unit = blockIdx.x * 4 + w;
  const bool isClass = unit < CP;
  const int c = unit;
  const int b = unit - CP;
  const bool pad = isClass && (c >= C_DIM);
  const float* src = isClass ? (sig + (size_t)c * K1) : (pe + (size_t)b * K1);

#pragma unroll
  for (int i = 0; i < 8; ++i) {
    int o = i * 256 + t * 4;
    f32x4 v = {0.f, 0.f, 0.f, 0.f};
    if (!pad) v = *(const f32x4*)(src + o);
    *(f32x4*)&LW[w][(o >> 6) * 72 + (o & 63)] = v;
  }
  __syncthreads();

  if (isClass) {
    float lv = (t < 32 && !pad) ? lr[c * 32 + t] : -3.0e38f;
    float mx = wmax(lv);
    float ev = (t < 32 && !pad) ? expf(lv - mx) : 0.f;
    float sden = wsum(ev);
    float res = pad ? 0.f : ev / sden;
    float lvn = __shfl_down(lv, 1, 64);
    if (t < 31) {
      expd[c * 32 + t] = pad ? 0.f : 1.f / (1.f + expf(-(lv - lvn)));
    } else if (t == 31) {
      expd[c * 32 + 31] = 0.f;
    }
    if (t < 32) {
      f32x4 sq = {0.f, 0.f, 0.f, 0.f};
#pragma unroll
      for (int i = 0; i < 16; ++i) {
        f32x4 v = *(const f32x4*)&LW[w][t * 72 + i * 4];
        sq += v * v;
      }
      float s = sq[0] + sq[1] + sq[2] + sq[3];
      float inv = 1.f / fmaxf(sqrtf(s), 1e-12f);
      AUX[w][t] = inv * res;
    }
  } else {
    if (t < 32) {
      f32x4 sq = {0.f, 0.f, 0.f, 0.f}, dt = {0.f, 0.f, 0.f, 0.f};
      const int tn = (t < 31) ? t + 1 : t;
#pragma unroll
      for (int i = 0; i < 16; ++i) {
        f32x4 v = *(const f32x4*)&LW[w][t * 72 + i * 4];
        f32x4 vn = *(const f32x4*)&LW[w][tn * 72 + i * 4];
        sq += v * v;
        dt += v * vn;
      }
      float s = sq[0] + sq[1] + sq[2] + sq[3];
      float d = dt[0] + dt[1] + dt[2] + dt[3];
      float nrm = sqrtf(s);
      AUX[w][t] = 1.f / fmaxf(nrm, 1e-12f);
      float nn = __shfl_down(nrm, 1, 64);
      if (t < 31)
        ssb[(size_t)b * 32 + t] =
            (d / (fmaxf(nrm, 1e-8f) * fmaxf(nn, 1e-8f)) + 1.f) * 0.5f;
      else
        ssb[(size_t)b * 32 + 31] = 0.f;
    }
  }
  __syncthreads();

  __hip_bfloat16* dst = isClass ? (wsig + (size_t)c * K1) : (pen + (size_t)b * K1);
  float es = 0.f, ls = 0.f;
#pragma unroll
  for (int l = 0; l < 32; ++l) {
    float v = LW[w][l * 72 + t];
    float m = AUX[w][l];
    dst[l * 64 + t] = __float2bfloat16(v * m);
    if (l < 16) es += v; else ls += v;
  }
  es *= (1.f / 16.f);
  ls *= (1.f / 16.f);
  float en = fmaxf(sqrtf(wsum(es * es)), 1e-12f);
  float ln2 = fmaxf(sqrtf(wsum(ls * ls)), 1e-12f);
  __hip_bfloat16* el = isClass ? (elc + (size_t)c * 128) : (elb + (size_t)b * 128);
  el[t] = __float2bfloat16(es / en);
  el[64 + t] = __float2bfloat16(ls / ln2);
}

// ---- main: 128x128 tile, 8 waves (64x32), BK=64, 4 buffers, depth-3 vmcnt ----
// R12 diagnosis: depth-1 at 1 blk/CU ingests only 8.25 B/cyc/CU (pipe empty
// during the vmcnt(0) wait). Fix = Little's law: keep 3 stages (96KB/CU) in
// flight via counted vmcnt(8) (T4). Traffic stays 256MB (128x128 reuse, R12).
// VGPR law (R6..R9): launch_bounds w=2 only; w=4 => 64-VGPR cap => spills.
__global__ __launch_bounds__(512, 2)
void basin_main(const __hip_bfloat16* __restrict__ pen,
                const __hip_bfloat16* __restrict__ wsig,
                const __hip_bfloat16* __restrict__ elb,
                const __hip_bfloat16* __restrict__ elc,
                const float* __restrict__ ssb,
                const float* __restrict__ expd,
                const float* __restrict__ cm,
                const float* __restrict__ proto,
                float* __restrict__ out) {
  __shared__ __align__(16) char smem[131072];  // 4 x (A 16KB + B 16KB)
  const int t = threadIdx.x;
  const int lane = t & 63;
  const int w = t >> 6;               // 0..7
  const int wm = w >> 2, wn = w & 3;  // 2M x 4N waves, each 64x32
  const int brow = blockIdx.x * 128;
  const int bcol = blockIdx.y * 128;
  // staging: 8 threads per 128B row (BK=64); granule-XOR swizzle g^=row&7
  // (both sides, rule 21). 4 insts/thread/stage (A:2, B:2), 8KB per inst.
  const int srow8 = t >> 3;                        // 0..63
  const int sel8 = (((t & 7) ^ (srow8 & 7)) << 3); // pre-swizzled src elem
  const int l15 = lane & 15;
  const int gq = lane >> 4;                        // 0..3

  const int rowA = (wm * 64 + l15) << 7;           // byte offset of A row
  const int rowB = (wn * 32 + l15) << 7;           // byte offset of B row (pre +16384)
  int xg[2];
#pragma unroll
  for (int kk = 0; kk < 2; ++kk) xg[kk] = (((kk * 4 + gq) ^ (l15 & 7)) << 4);

  f32x4 acc1[4][2] = {};
  f32x4 acc2[4][2] = {};

// BI literal. Buffer at BI*32768: A 16KB then B 16KB.
#define STAGE_T(kt, BI)                                                                   \
  do {                                                                                    \
    _Pragma("unroll") for (int i = 0; i < 2; ++i) {                                       \
      load_lds16(pen + (size_t)(brow + i * 64 + srow8) * K1 + (kt) * 64 + sel8,           \
                 smem + (BI) * 32768 + i * 8192 + t * 16);                                \
      load_lds16(wsig + (size_t)(bcol + i * 64 + srow8) * K1 + (kt) * 64 + sel8,          \
                 smem + (BI) * 32768 + 16384 + i * 8192 + t * 16);                        \
    }                                                                                     \
  } while (0)

#define STAGE_H(s, BI)                                                                    \
  do {                                                                                    \
    _Pragma("unroll") for (int i = 0; i < 2; ++i) {                                       \
      load_lds16(elb + (size_t)(brow + i * 64 + srow8) * 128 + (s) * 64 + sel8,           \
                 smem + (BI) * 32768 + i * 8192 + t * 16);                                \
      load_lds16(elc + (size_t)(bcol + i * 64 + srow8) * 128 + (s) * 64 + sel8,           \
                 smem + (BI) * 32768 + 16384 + i * 8192 + t * 16);                        \
    }                                                                                     \
  } while (0)

// per step: 2 kk x (4 A + 2 B ds_read_b128, 8 MFMA) = 12 ds + 16 MFMA
#define COMPUTE(ACC, BI)                                                                  \
  do {                                                                                    \
    _Pragma("unroll") for (int kk = 0; kk < 2; ++kk) {                                    \
      bf16x8 af[4], bg[2];                                                                \
      _Pragma("unroll") for (int m = 0; m < 4; ++m)                                       \
          af[m] = *(const bf16x8*)(smem + (BI) * 32768 + rowA + m * 2048 + xg[kk]);       \
      _Pragma("unroll") for (int n = 0; n < 2; ++n)                                       \
          bg[n] = *(const bf16x8*)(smem + (BI) * 32768 + 16384 + rowB + n * 2048 + xg[kk]); \
      _Pragma("unroll") for (int m = 0; m < 4; ++m)                                       \
        _Pragma("unroll") for (int n = 0; n < 2; ++n)                                     \
          ACC[m][n] = __builtin_amdgcn_mfma_f32_16x16x32_bf16(af[m], bg[n], ACC[m][n], 0, 0, 0); \
    }                                                                                     \
  } while (0)

#define VMW(N) asm volatile("s_waitcnt vmcnt(" #N ")" ::: "memory")
#define BAR()                    \
  __builtin_amdgcn_s_barrier();  \
  __builtin_amdgcn_sched_barrier(0)

// steady-state step: 3 stages in flight (12 insts); wait oldest (stage kt)
#define KSTEP_S(kt, BI, NXT)                                                              \
  do {                                                                                    \
    VMW(8);                                                                               \
    BAR();                                                                                \
    STAGE_T((kt) + 3, NXT);                                                               \
    COMPUTE(acc1, BI);                                                                    \
  } while (0)

  // ---- triadic GEMM: K=2048, 32 steps of BK=64, depth-3 pipeline ----
  STAGE_T(0, 0);
  STAGE_T(1, 1);
  STAGE_T(2, 2);
  for (int kt = 0; kt < 28; kt += 4) {  // steps 0..27, stages 3..30
    KSTEP_S(kt, 0, 3);
    KSTEP_S(kt + 1, 1, 0);
    KSTEP_S(kt + 2, 2, 1);
    KSTEP_S(kt + 3, 3, 2);
  }
  // step 28 (issues stage 31), then drain 29/30/31
  VMW(8); BAR(); STAGE_T(31, 3); COMPUTE(acc1, 0);
  VMW(8); BAR(); COMPUTE(acc1, 1);
  VMW(4); BAR(); COMPUTE(acc1, 2);
  VMW(0); BAR(); COMPUTE(acc1, 3);

  // ---- hier GEMM: K=128 = 2 steps of BK=64 (buffers 0,1 free: reads done
  // before the step-29/30 barriers) ----
  STAGE_H(0, 0);
  STAGE_H(1, 1);
  VMW(4); BAR();
  COMPUTE(acc2, 0);
  VMW(0); BAR();
  COMPUTE(acc2, 1);
  __syncthreads();  // done reading before epilogue overwrites smem

  // ---- epilogue: stage ss/exp rows + cantor scalars in LDS ----
  float* ss_l = (float*)smem;            // [128][36] padded (18432B)
  float* ex_l = (float*)(smem + 18432);  // [128][36]
  float* cm_l = (float*)(smem + 36864);  // [128]
  float* pr_l = (float*)(smem + 37376);  // [128]
  for (int i = t; i < 4096; i += 512) {
    int r = i >> 5, l = i & 31;
    ss_l[r * 36 + l] = ssb[(size_t)(brow + r) * 32 + l];
    ex_l[r * 36 + l] = expd[(size_t)(bcol + r) * 32 + l];
  }
  if (t < 128) cm_l[t] = cm[brow + t];
  else if (t < 256) pr_l[t - 128] = (bcol + t - 128 < C_DIM) ? proto[bcol + t - 128] : 0.f;
  __syncthreads();

  const int col0 = wn * 32 + l15;
  const int row0 = wm * 64 + (gq << 2);
#pragma unroll
  for (int m = 0; m < 4; ++m) {
    float ssum[4][2];
#pragma unroll
    for (int j = 0; j < 4; ++j)
#pragma unroll
      for (int n = 0; n < 2; ++n) ssum[j][n] = 0.f;
#pragma unroll
    for (int l4 = 0; l4 < 32; l4 += 4) {
      f32x4 evv[2], sv[4];
#pragma unroll
      for (int n = 0; n < 2; ++n)
        evv[n] = *(const f32x4*)&ex_l[(col0 + n * 16) * 36 + l4];
#pragma unroll
      for (int j = 0; j < 4; ++j)
        sv[j] = *(const f32x4*)&ss_l[(row0 + m * 16 + j) * 36 + l4];
#pragma unroll
      for (int j = 0; j < 4; ++j)
#pragma unroll
        for (int n = 0; n < 2; ++n) {
          ssum[j][n] += fabsf(sv[j][0] - evv[n][0]) + fabsf(sv[j][1] - evv[n][1]) +
                        fabsf(sv[j][2] - evv[n][2]) + fabsf(sv[j][3] - evv[n][3]);
        }
    }
#pragma unroll
    for (int j = 0; j < 4; ++j) {
      int rloc = row0 + m * 16 + j;
      float cmv = cm_l[rloc];
#pragma unroll
      for (int n = 0; n < 2; ++n) {
        int cloc = col0 + n * 16;
        int cg = bcol + cloc;
        float tria = fminf(fmaxf(0.5f + 0.5f * acc1[m][n][j], EPS), 1.0f);
        float hier = fminf(fmaxf(0.5f + 0.25f * acc2[m][n][j], EPS), 1.0f);
        float sc = fminf(fmaxf(1.0f - ssum[j][n] * (1.0f / 31.0f), EPS), 1.0f);
        float d = cmv - pr_l[cloc];
        float cc = __expf(d * d * -10.0f) + 1e-8f;
        cc = fminf(fmaxf(cc, EPS), 1.0f);
        float p = tria * sc * cc * hier;
        if (cg < C_DIM)
          out[(size_t)(brow + rloc) * C_DIM + cg] = sqrtf(sqrtf(p));
      }
    }
  }
}

extern "C" void kernel_launch(void* const* d_in, const int* in_sizes, int n_in,
                              void* d_out, int out_size, void* d_ws, size_t ws_size,
                              hipStream_t stream) {
  (void)in_sizes; (void)n_in; (void)out_size; (void)ws_size;
  const float* pe = (const float*)d_in[0];     // B x L x F
  const float* cm = (const float*)d_in[1];     // B
  const float* sig = (const float*)d_in[2];    // C x L x F
  const float* proto = (const float*)d_in[3];  // C
  const float* lr = (const float*)d_in[4];     // C x L
  float* out = (float*)d_out;
  char* ws = (char*)d_ws;

  __hip_bfloat16* wsig = (__hip_bfloat16*)(ws);               // CP*2048*2 = 4 MiB
  __hip_bfloat16* pen = (__hip_bfloat16*)(ws + 4194304);      // B*2048*2 = 16 MiB
  __hip_bfloat16* elb = (__hip_bfloat16*)(ws + 20971520);     // B*128*2  = 1 MiB
  __hip_bfloat16* elc = (__hip_bfloat16*)(ws + 22020096);     // CP*128*2 = 256 KiB
  float* ssb = (float*)(ws + 22282240);                       // B*32*4   = 512 KiB
  float* expd = (float*)(ws + 22806528);                      // CP*32*4  = 128 KiB

  prep_all<<<(CP + B_DIM) / 4, 256, 0, stream>>>(sig, lr, pe, wsig, expd, elc, pen, ssb, elb);
  dim3 grid(B_DIM / 128, CP / 128);
  basin_main<<<grid, 512, 0, stream>>>(pen, wsig, elb, elc, ssb, expd, cm, proto, out);
}